// Round 2
// baseline (114.715 us; speedup 1.0000x reference)
//
#include <hip/hip_runtime.h>

// Viterbi trellis quantizer: S=1024 states, K=2 (4 predecessors), CHUNK=4,
// block_size=16 -> T=64 steps/chain, B=4096 chains (16x16 blocks of 1024^2).
//
// One 64-lane wave per chain. beta-formulation: beta[s] = -(alpha[s]-||x||^2)/2,
//   beta_new[s] = M[s>>2] + (cb[s]·x + h[s]),  h = -||cb||^2/2,
// grouped max M[p] = max_j beta[p + 256 j], 2-bit backpointers per group.
//
// R4 changes. R3 evidence: removing the out-of-loop pin changed NOTHING
// (VGPR_Count 60, occ 30%, 57.5us) -> the allocator banks the 80-value
// codebook in the AGPR half of the unified file on its own; measured issue
// cycles imply ~260 VALU/step vs ~125 in source (accvgpr_read traffic),
// and granule-rounded arch+acc (~144) caps occupancy at ~3 waves/EU.
//   1. Pin the codebook INSIDE the t-loop (empty "+v" asm each iteration):
//      AGPR-banking would now cost 80 moves/step, so the allocator must keep
//      it in arch VGPRs. Demand ~115 fits the 128-reg waves_per_eu(4,4)
//      budget -> 4 waves/EU, all 4096 waves co-resident, no tail.
//      Tripwire if wrong: WRITE_SIZE > 5120 KB (scratch spill).
//   2. v_pk_fma_f32: codebook repacked as (c,c+1) float2 pairs; the 64 FMA +
//      16 add become 32 pk_fma + 8 pk_add via __builtin_elementwise_fma on
//      ext_vector float2. IEEE-identical per half, same chain order, same
//      max/select -> decisions bit-identical to the passing R3 kernel.

#define COLS      1024
#define T_STEPS   64
#define REC_SIZE  (1024 * 1024)

typedef float v2f __attribute__((ext_vector_type(2)));

__global__ __launch_bounds__(128)
__attribute__((amdgpu_waves_per_eu(4, 4)))
void viterbi_q(
    const float* __restrict__ arr,
    const float* __restrict__ cbook,
    float* __restrict__ out)
{
    const int tid   = threadIdx.x;
    const int wid   = tid >> 6;      // chain slot in block (0..1)
    const int lane  = tid & 63;
    const int chain = (blockIdx.x << 1) | wid;   // 0..4095
    const int rb    = chain >> 6;    // block-row
    const int cb    = chain & 63;    // block-col

    __shared__ __align__(16) float tile[2][256];   // x chunks for the chain
    __shared__ __align__(16) float Mst[2][256];    // grouped-max state M[p]
    __shared__ unsigned char Jb[2][63 * 64];       // packed backpointers
    __shared__ int st_lds[2][64];                  // traced-back states

    // ---- stage this chain's 16x16 tile into LDS (tile[e], e = r*16 + c) ----
    {
        const int r  = lane >> 2;
        const int c4 = (lane & 3) << 2;
        float4 v = *(const float4*)(arr + (rb * 16 + r) * COLS + cb * 16 + c4);
        *(float4*)&tile[wid][lane << 2] = v;
    }
    // M starts at 0: iteration t=0 then computes beta0 = cb·x0 + h exactly.
    *(float4*)&Mst[wid][lane << 2] = make_float4(0.f, 0.f, 0.f, 0.f);

    // ---- codebook rows, packed for v_pk_fma_f32 ----
    // state s = 4*lane + c + 256*j; pair (c=2p, c=2p+1):
    //   A2[j][p][w] = { row(2p,j).w , row(2p+1,j).w }   (w = x,y,z,w)
    //   H2[j][p]    = { h(2p,j)     , h(2p+1,j)      }
    v2f A2[4][2][4];
    v2f H2[4][2];
    #pragma unroll
    for (int j = 0; j < 4; ++j) {
        #pragma unroll
        for (int p = 0; p < 2; ++p) {
            const int r0 = (lane << 2) + 2 * p + (j << 8);
            float4 v0 = *(const float4*)(cbook + r0 * 4);
            float4 v1 = *(const float4*)(cbook + (r0 + 1) * 4);
            A2[j][p][0] = (v2f){v0.x, v1.x};
            A2[j][p][1] = (v2f){v0.y, v1.y};
            A2[j][p][2] = (v2f){v0.z, v1.z};
            A2[j][p][3] = (v2f){v0.w, v1.w};
            H2[j][p] = (v2f){
                -0.5f * (v0.x * v0.x + v0.y * v0.y + v0.z * v0.z + v0.w * v0.w),
                -0.5f * (v1.x * v1.x + v1.y * v1.y + v1.z * v1.z + v1.w * v1.w)};
        }
    }

    // hoisted LDS pointers
    const float* __restrict__ tilep = &tile[wid][0];
    float* __restrict__ Mp          = &Mst[wid][0];
    unsigned char* __restrict__ Jp  = &Jb[wid][0];

    // ---- forward recursion, t = 0..62: store backpointers J_t ----
    #pragma unroll 1
    for (int t = 0; t < T_STEPS - 1; ++t) {
        // In-loop pin: forces the packed codebook to stay in ARCH VGPRs
        // (AGPR-banking would cost 80 cross-file moves per step).
        #pragma unroll
        for (int j = 0; j < 4; ++j) {
            asm volatile(""
                : "+v"(A2[j][0][0]), "+v"(A2[j][0][1]),
                  "+v"(A2[j][0][2]), "+v"(A2[j][0][3]),
                  "+v"(A2[j][1][0]), "+v"(A2[j][1][1]),
                  "+v"(A2[j][1][2]), "+v"(A2[j][1][3]),
                  "+v"(H2[j][0]), "+v"(H2[j][1]));
        }

        const float4 xt = *(const float4*)&tilep[t << 2];   // broadcast read
        const v2f xx = (v2f){xt.x, xt.x};
        const v2f xy = (v2f){xt.y, xt.y};
        const v2f xz = (v2f){xt.z, xt.z};
        const v2f xw = (v2f){xt.w, xt.w};

        v2f mj2[4];
        #pragma unroll
        for (int j = 0; j < 4; ++j) {
            const float m = Mp[lane + 64 * j];
            mj2[j] = (v2f){m, m};
        }

        float nm[4];
        unsigned bp = 0;
        #pragma unroll
        for (int p = 0; p < 2; ++p) {
            v2f cand2[4];
            #pragma unroll
            for (int j = 0; j < 4; ++j) {
                v2f acc = __builtin_elementwise_fma(A2[j][p][0], xx, H2[j][p]);
                acc = __builtin_elementwise_fma(A2[j][p][1], xy, acc);
                acc = __builtin_elementwise_fma(A2[j][p][2], xz, acc);
                acc = __builtin_elementwise_fma(A2[j][p][3], xw, acc);
                cand2[j] = acc + mj2[j];
            }
            #pragma unroll
            for (int half = 0; half < 2; ++half) {
                const int c = 2 * p + half;
                const float c0 = cand2[0][half];
                const float c1 = cand2[1][half];
                const float c2 = cand2[2][half];
                const float c3 = cand2[3][half];
                const float v = fmaxf(fmaxf(fmaxf(c0, c1), c2), c3);
                // first-max index == reference's first-min over alpha cands
                const int j = (c0 == v) ? 0
                            : (c1 == v) ? 1
                            : (c2 == v) ? 2 : 3;
                nm[c] = v;
                bp |= (unsigned)j << (2 * c);
            }
        }
        // wave-lockstep: all lanes issued their M reads above before this write
        *(float4*)&Mp[lane << 2] = make_float4(nm[0], nm[1], nm[2], nm[3]);
        Jp[t * 64 + lane] = (unsigned char)bp;
    }

    // ---- final step t = 63: full argmax over beta_63[0..1023] ----
    int bests;
    {
        const int t = T_STEPS - 1;
        const float4 xt = *(const float4*)&tilep[t << 2];
        const v2f xx = (v2f){xt.x, xt.x};
        const v2f xy = (v2f){xt.y, xt.y};
        const v2f xz = (v2f){xt.z, xt.z};
        const v2f xw = (v2f){xt.w, xt.w};

        v2f mj2[4];
        #pragma unroll
        for (int j = 0; j < 4; ++j) {
            const float m = Mp[lane + 64 * j];
            mj2[j] = (v2f){m, m};
        }

        float cda[4][4];   // [j][c] candidate beta values
        #pragma unroll
        for (int p = 0; p < 2; ++p) {
            #pragma unroll
            for (int j = 0; j < 4; ++j) {
                v2f acc = __builtin_elementwise_fma(A2[j][p][0], xx, H2[j][p]);
                acc = __builtin_elementwise_fma(A2[j][p][1], xy, acc);
                acc = __builtin_elementwise_fma(A2[j][p][2], xz, acc);
                acc = __builtin_elementwise_fma(A2[j][p][3], xw, acc);
                v2f q = acc + mj2[j];
                cda[j][2 * p]     = q[0];
                cda[j][2 * p + 1] = q[1];
            }
        }

        float bv = -3.4e38f;
        int   bs = 0;
        #pragma unroll
        for (int j = 0; j < 4; ++j) {      // s ascends with (j, c): first-max ok
            #pragma unroll
            for (int c = 0; c < 4; ++c) {
                const float acc = cda[j][c];
                if (acc > bv) { bv = acc; bs = (lane << 2) + c + (j << 8); }
            }
        }
        // lexicographic (value desc, state asc) butterfly across the wave
        #pragma unroll
        for (int off = 32; off > 0; off >>= 1) {
            const float ov = __shfl_xor(bv, off, 64);
            const int   os = __shfl_xor(bs, off, 64);
            if (ov > bv || (ov == bv && os < bs)) { bv = ov; bs = os; }
        }
        bests = bs;
    }

    // ---- traceback (serial, lane 0 of each wave) ----
    if (lane == 0) {
        int s = bests;
        st_lds[wid][T_STEPS - 1] = s;
        for (int i = T_STEPS - 2; i >= 0; --i) {
            const int p = s >> 2;
            const unsigned byte = Jp[i * 64 + (p >> 2)];
            const int j = (byte >> (2 * (p & 3))) & 3;
            s = p + (j << 8);
            st_lds[wid][i] = s;
        }
    }
    // NO barrier: st_lds[wid] is written by lane 0 of THIS wave and read by
    // the same wave below; wave-lockstep + in-order LDS makes it visible.

    // ---- outputs: lane i handles step t = i ----
    const int st = st_lds[wid][lane];
    // states_out flat: REC_SIZE + chain*64 + t   (stored as float values)
    out[REC_SIZE + chain * 64 + lane] = (float)st;
    // rec: step t covers elements e = 4t..4t+3 -> row t>>2, cols 4*(t&3)..+3
    const float4 v = *(const float4*)(cbook + st * 4);
    const int r  = lane >> 2;
    const int c4 = (lane & 3) << 2;
    *(float4*)(out + (rb * 16 + r) * COLS + cb * 16 + c4) = v;
}

extern "C" void kernel_launch(void* const* d_in, const int* in_sizes, int n_in,
                              void* d_out, int out_size, void* d_ws, size_t ws_size,
                              hipStream_t stream)
{
    const float* arr   = (const float*)d_in[0];
    const float* cbook = (const float*)d_in[1];
    float* out = (float*)d_out;
    // 4096 chains, 2 chains (waves) per 128-thread block -> 2048 blocks
    viterbi_q<<<dim3(2048), dim3(128), 0, stream>>>(arr, cbook, out);
}

// Round 3
// 113.940 us; speedup vs baseline: 1.0068x; 1.0068x over previous
//
#include <hip/hip_runtime.h>

// Viterbi trellis quantizer: S=1024 states, K=2 (4 predecessors), CHUNK=4,
// block_size=16 -> T=64 steps/chain, B=4096 chains (16x16 blocks of 1024^2).
//
// One 64-lane wave per chain. beta-formulation: beta[s] = -(alpha[s]-||x||^2)/2,
//   beta_new[s] = M[s>>2] + (cb[s]·x + h[s]),  h = -||cb||^2/2,
// grouped max M[p] = max_j beta[p + 256 j], 2-bit backpointers per group.
//
// R5. Evidence so far:
//  - R2 (out-of-loop pin) == R3 (no pin): 57.5us, VGPR 60, VALU ~92% ->
//    AGPR-banking of the codebook is FREE (CDNA VALU reads ACC regs directly).
//  - R4 (in-loop pin + pk_fma): 68us, VALU 69% -> the per-iteration asm is a
//    scheduling wall (forces copy webs + blocks cross-iteration overlap).
//    BUT R4 passed with absmax 0.0 -> pk_fma numerics are bit-exact.
// R5 = R4 minus the poison:
//  1. ALL pin asm deleted; allocator free to bank codebook in AGPRs.
//  2. pk_fma kept: 64 FMA + 16 add -> 32 v_pk_fma_f32 + 8 v_pk_add_f32.
//  3. #pragma unroll 4 on the t-loop: LDS offsets fold to immediates and the
//     M-independent work (xt load, 16 dot products) software-pipelines under
//     the previous step's M write->read LDS round trip.
// Tripwire: WRITE_SIZE > 5120 KB means unroll-4 caused scratch spill -> unroll 2.

#define COLS      1024
#define T_STEPS   64
#define REC_SIZE  (1024 * 1024)

typedef float v2f __attribute__((ext_vector_type(2)));

__global__ __launch_bounds__(128)
__attribute__((amdgpu_waves_per_eu(4, 4)))
void viterbi_q(
    const float* __restrict__ arr,
    const float* __restrict__ cbook,
    float* __restrict__ out)
{
    const int tid   = threadIdx.x;
    const int wid   = tid >> 6;      // chain slot in block (0..1)
    const int lane  = tid & 63;
    const int chain = (blockIdx.x << 1) | wid;   // 0..4095
    const int rb    = chain >> 6;    // block-row
    const int cb    = chain & 63;    // block-col

    __shared__ __align__(16) float tile[2][256];   // x chunks for the chain
    __shared__ __align__(16) float Mst[2][256];    // grouped-max state M[p]
    __shared__ unsigned char Jb[2][63 * 64];       // packed backpointers
    __shared__ int st_lds[2][64];                  // traced-back states

    // ---- stage this chain's 16x16 tile into LDS (tile[e], e = r*16 + c) ----
    {
        const int r  = lane >> 2;
        const int c4 = (lane & 3) << 2;
        float4 v = *(const float4*)(arr + (rb * 16 + r) * COLS + cb * 16 + c4);
        *(float4*)&tile[wid][lane << 2] = v;
    }
    // M starts at 0: iteration t=0 then computes beta0 = cb·x0 + h exactly.
    *(float4*)&Mst[wid][lane << 2] = make_float4(0.f, 0.f, 0.f, 0.f);

    // ---- codebook rows, packed for v_pk_fma_f32 ----
    // state s = 4*lane + c + 256*j; pair (c=2p, c=2p+1):
    //   A2[j][p][w] = { row(2p,j).w , row(2p+1,j).w }   (w = x,y,z,w)
    //   H2[j][p]    = { h(2p,j)     , h(2p+1,j)      }
    v2f A2[4][2][4];
    v2f H2[4][2];
    #pragma unroll
    for (int j = 0; j < 4; ++j) {
        #pragma unroll
        for (int p = 0; p < 2; ++p) {
            const int r0 = (lane << 2) + 2 * p + (j << 8);
            float4 v0 = *(const float4*)(cbook + r0 * 4);
            float4 v1 = *(const float4*)(cbook + (r0 + 1) * 4);
            A2[j][p][0] = (v2f){v0.x, v1.x};
            A2[j][p][1] = (v2f){v0.y, v1.y};
            A2[j][p][2] = (v2f){v0.z, v1.z};
            A2[j][p][3] = (v2f){v0.w, v1.w};
            H2[j][p] = (v2f){
                -0.5f * (v0.x * v0.x + v0.y * v0.y + v0.z * v0.z + v0.w * v0.w),
                -0.5f * (v1.x * v1.x + v1.y * v1.y + v1.z * v1.z + v1.w * v1.w)};
        }
    }

    // hoisted LDS pointers
    const float* __restrict__ tilep = &tile[wid][0];
    float* __restrict__ Mp          = &Mst[wid][0];
    unsigned char* __restrict__ Jp  = &Jb[wid][0];

    // ---- forward recursion, t = 0..62: store backpointers J_t ----
    #pragma unroll 4
    for (int t = 0; t < T_STEPS - 1; ++t) {
        const float4 xt = *(const float4*)&tilep[t << 2];   // broadcast read
        const v2f xx = (v2f){xt.x, xt.x};
        const v2f xy = (v2f){xt.y, xt.y};
        const v2f xz = (v2f){xt.z, xt.z};
        const v2f xw = (v2f){xt.w, xt.w};

        v2f mj2[4];
        #pragma unroll
        for (int j = 0; j < 4; ++j) {
            const float m = Mp[lane + 64 * j];
            mj2[j] = (v2f){m, m};
        }

        float nm[4];
        unsigned bp = 0;
        #pragma unroll
        for (int p = 0; p < 2; ++p) {
            v2f cand2[4];
            #pragma unroll
            for (int j = 0; j < 4; ++j) {
                v2f acc = __builtin_elementwise_fma(A2[j][p][0], xx, H2[j][p]);
                acc = __builtin_elementwise_fma(A2[j][p][1], xy, acc);
                acc = __builtin_elementwise_fma(A2[j][p][2], xz, acc);
                acc = __builtin_elementwise_fma(A2[j][p][3], xw, acc);
                cand2[j] = acc + mj2[j];
            }
            #pragma unroll
            for (int half = 0; half < 2; ++half) {
                const int c = 2 * p + half;
                const float c0 = cand2[0][half];
                const float c1 = cand2[1][half];
                const float c2 = cand2[2][half];
                const float c3 = cand2[3][half];
                // chained -> v_max3_f32 + v_max_f32 (max exact, any tree ok)
                const float v = fmaxf(fmaxf(fmaxf(c0, c1), c2), c3);
                // first-max index == reference's first-min over alpha cands
                const int j = (c0 == v) ? 0
                            : (c1 == v) ? 1
                            : (c2 == v) ? 2 : 3;
                nm[c] = v;
                bp |= (unsigned)j << (2 * c);
            }
        }
        // wave-lockstep: all lanes issued their M reads above before this write
        *(float4*)&Mp[lane << 2] = make_float4(nm[0], nm[1], nm[2], nm[3]);
        Jp[t * 64 + lane] = (unsigned char)bp;
    }

    // ---- final step t = 63: full argmax over beta_63[0..1023] ----
    int bests;
    {
        const int t = T_STEPS - 1;
        const float4 xt = *(const float4*)&tilep[t << 2];
        const v2f xx = (v2f){xt.x, xt.x};
        const v2f xy = (v2f){xt.y, xt.y};
        const v2f xz = (v2f){xt.z, xt.z};
        const v2f xw = (v2f){xt.w, xt.w};

        v2f mj2[4];
        #pragma unroll
        for (int j = 0; j < 4; ++j) {
            const float m = Mp[lane + 64 * j];
            mj2[j] = (v2f){m, m};
        }

        float cda[4][4];   // [j][c] candidate beta values
        #pragma unroll
        for (int p = 0; p < 2; ++p) {
            #pragma unroll
            for (int j = 0; j < 4; ++j) {
                v2f acc = __builtin_elementwise_fma(A2[j][p][0], xx, H2[j][p]);
                acc = __builtin_elementwise_fma(A2[j][p][1], xy, acc);
                acc = __builtin_elementwise_fma(A2[j][p][2], xz, acc);
                acc = __builtin_elementwise_fma(A2[j][p][3], xw, acc);
                v2f q = acc + mj2[j];
                cda[j][2 * p]     = q[0];
                cda[j][2 * p + 1] = q[1];
            }
        }

        float bv = -3.4e38f;
        int   bs = 0;
        #pragma unroll
        for (int j = 0; j < 4; ++j) {      // s ascends with (j, c): first-max ok
            #pragma unroll
            for (int c = 0; c < 4; ++c) {
                const float acc = cda[j][c];
                if (acc > bv) { bv = acc; bs = (lane << 2) + c + (j << 8); }
            }
        }
        // lexicographic (value desc, state asc) butterfly across the wave
        #pragma unroll
        for (int off = 32; off > 0; off >>= 1) {
            const float ov = __shfl_xor(bv, off, 64);
            const int   os = __shfl_xor(bs, off, 64);
            if (ov > bv || (ov == bv && os < bs)) { bv = ov; bs = os; }
        }
        bests = bs;
    }

    // ---- traceback (serial, lane 0 of each wave) ----
    if (lane == 0) {
        int s = bests;
        st_lds[wid][T_STEPS - 1] = s;
        for (int i = T_STEPS - 2; i >= 0; --i) {
            const int p = s >> 2;
            const unsigned byte = Jp[i * 64 + (p >> 2)];
            const int j = (byte >> (2 * (p & 3))) & 3;
            s = p + (j << 8);
            st_lds[wid][i] = s;
        }
    }
    // NO barrier: st_lds[wid] is written by lane 0 of THIS wave and read by
    // the same wave below; wave-lockstep + in-order LDS makes it visible.

    // ---- outputs: lane i handles step t = i ----
    const int st = st_lds[wid][lane];
    // states_out flat: REC_SIZE + chain*64 + t   (stored as float values)
    out[REC_SIZE + chain * 64 + lane] = (float)st;
    // rec: step t covers elements e = 4t..4t+3 -> row t>>2, cols 4*(t&3)..+3
    const float4 v = *(const float4*)(cbook + st * 4);
    const int r  = lane >> 2;
    const int c4 = (lane & 3) << 2;
    *(float4*)(out + (rb * 16 + r) * COLS + cb * 16 + c4) = v;
}

extern "C" void kernel_launch(void* const* d_in, const int* in_sizes, int n_in,
                              void* d_out, int out_size, void* d_ws, size_t ws_size,
                              hipStream_t stream)
{
    const float* arr   = (const float*)d_in[0];
    const float* cbook = (const float*)d_in[1];
    float* out = (float*)d_out;
    // 4096 chains, 2 chains (waves) per 128-thread block -> 2048 blocks
    viterbi_q<<<dim3(2048), dim3(128), 0, stream>>>(arr, cbook, out);
}